// Round 11
// baseline (155.973 us; speedup 1.0000x reference)
//
#include <hip/hip_runtime.h>
#include <math.h>

typedef __attribute__((ext_vector_type(8))) short short8;
typedef __attribute__((ext_vector_type(4))) float f32x4;
typedef unsigned int uint;
typedef unsigned short ushort;

#define T1 4.0f
#define T2 5.0f
#define T3 10.0f
#define EPSF 1e-8f
#define SST 68   // S^T row stride (floats): rows 16B-aligned

__device__ inline ushort f2bf(float x) {
    union { float f; uint u; } a; a.f = x;
    uint r = a.u + 0x7FFFu + ((a.u >> 16) & 1u);
    return (ushort)(r >> 16);
}
__device__ inline float bf2f(ushort h) {
    union { uint u; float f; } a; a.u = ((uint)h) << 16;
    return a.f;
}

// async global->LDS, 16B per lane; LDS dest is wave-uniform base + lane*16 (implicit)
#define GLDS(gsrc, ldst) \
    __builtin_amdgcn_global_load_lds( \
        (const __attribute__((address_space(1))) uint*)(gsrc), \
        (__attribute__((address_space(3))) uint*)(ldst), 16, 0, 0)

// ---------------- prep: fp32 -> bf16 hi/lo in LDS-image layout (+ w1 norms) ----------------
// Layout per row-block idx: [kc 0..15][row r 0..63][4 chunks of 16B, logical chunk c at
// physical slot (c + (r>>1)) & 3]  => 65536 B per idx.  (kept separate from G-compute:
// r6->r7 showed fusing G into prep slowed pair 76.6->71 via L2-state effects)
__global__ __launch_bounds__(256) void prep_kernel(
        const float* __restrict__ ecg, const float* __restrict__ sent,
        char* __restrict__ EH, char* __restrict__ EL,
        char* __restrict__ SH, char* __restrict__ SL, float* __restrict__ w1) {
    __shared__ float partial[256];
    const int bid = blockIdx.x;
    const int tensor = bid >> 6, idx = bid & 63;
    const float* src = (tensor ? sent : ecg) + (size_t)idx * 32768;
    char* dh = (tensor ? SH : EH) + (size_t)idx * 65536;
    char* dl = (tensor ? SL : EL) + (size_t)idx * 65536;
    const int tid = threadIdx.x;
    const int r = tid & 63;
    float s2 = 0.f;
    #pragma unroll
    for (int it = 0; it < 4; it++) {
        int kc = it * 4 + (tid >> 6);
        const float* p = src + r * 512 + kc * 32;
        char* oh = dh + kc * 4096 + r * 64;
        char* ol = dl + kc * 4096 + r * 64;
        #pragma unroll
        for (int c = 0; c < 4; c++) {
            float4 v0 = *(const float4*)(p + c * 8);
            float4 v1 = *(const float4*)(p + c * 8 + 4);
            float x[8] = {v0.x, v0.y, v0.z, v0.w, v1.x, v1.y, v1.z, v1.w};
            uint hw[4], lw[4];
            #pragma unroll
            for (int e = 0; e < 4; e++) {
                float a0 = x[2 * e], a1 = x[2 * e + 1];
                ushort h0 = f2bf(a0), h1 = f2bf(a1);
                hw[e] = (uint)h0 | ((uint)h1 << 16);
                ushort l0 = f2bf(a0 - bf2f(h0)), l1 = f2bf(a1 - bf2f(h1));
                lw[e] = (uint)l0 | ((uint)l1 << 16);
                s2 += a0 * a0 + a1 * a1;
            }
            int phys = (c + (r >> 1)) & 3;
            uint4 H; H.x = hw[0]; H.y = hw[1]; H.z = hw[2]; H.w = hw[3];
            *(uint4*)(oh + phys * 16) = H;
            uint4 L; L.x = lw[0]; L.y = lw[1]; L.z = lw[2]; L.w = lw[3];
            *(uint4*)(ol + phys * 16) = L;
        }
    }
    partial[tid] = s2;
    __syncthreads();
    if (tensor == 1 && tid < 64) {
        float t = partial[tid] + partial[tid + 64] + partial[tid + 128] + partial[tid + 192];
        w1[idx * 64 + tid] = sqrtf(t);
    }
}

// ---------------- G_j = E_j E_j^T, barrier-free, 256 blocks (r8, kept: -3.4us non-pair) ----------------
// block b: j = b>>2, row band tq = b&3 (16 rows). Wave w: output cols 16w..16w+16.
// Fragments read directly from global (L2-hot). No LDS, no barriers -> latency-pipelined.
__global__ __launch_bounds__(256) void gprep_kernel(
        const char* __restrict__ EH, const char* __restrict__ EL, char* __restrict__ Gp) {
    const int b = blockIdx.x;
    const int j = b >> 2, tq = b & 3;
    const int tid = threadIdx.x;
    const int wv = tid >> 6, lane = tid & 63;
    const int quad = lane >> 4, ln = lane & 15;
    const char* srcH = EH + (size_t)j * 65536;
    const char* srcL = EL + (size_t)j * 65536;

    const int Ra = 16 * tq + ln;
    const int ao = Ra * 64 + ((quad + (Ra >> 1)) & 3) * 16;
    const int Rb = 16 * wv + ln;
    const int bo = Rb * 64 + ((quad + (Rb >> 1)) & 3) * 16;

    f32x4 acc = (f32x4){0.f, 0.f, 0.f, 0.f};
    #pragma unroll 4
    for (int kc = 0; kc < 16; kc++) {
        const char* ph = srcH + (size_t)kc * 4096;
        const char* pl = srcL + (size_t)kc * 4096;
        short8 ah = *(const short8*)(ph + ao);
        short8 al = *(const short8*)(pl + ao);
        short8 bh = *(const short8*)(ph + bo);
        short8 bl = *(const short8*)(pl + bo);
        acc = __builtin_amdgcn_mfma_f32_16x16x32_bf16(ah, bh, acc, 0, 0, 0);
        acc = __builtin_amdgcn_mfma_f32_16x16x32_bf16(ah, bl, acc, 0, 0, 0);
        acc = __builtin_amdgcn_mfma_f32_16x16x32_bf16(al, bh, acc, 0, 0, 0);
    }
    #pragma unroll
    for (int rr = 0; rr < 4; rr++) {
        int t = 16 * tq + quad * 4 + rr;
        int u = 16 * wv + ln;
        float g = acc[rr];
        ushort h = f2bf(g);
        ushort l = f2bf(g - bf2f(h));
        char* base = Gp + (size_t)j * 16384 + t * 128 + (((u >> 3) + t) & 7) * 16 + (u & 7) * 2;
        *(ushort*)base = h;
        *(ushort*)(base + 8192) = l;
    }
}

// ---------------- main: one block per 2x2 pairs (128x128 GEMM1 tile) ----------------
// r9 base (measured 70.5-70.7us) + in-register fold: the w2 fold is computed directly
// from acc2 in MFMA layout (32 scalar P reads + shfl-reduce over t), removing the yT
// LDS round-trip and 2 of 7 barriers per pair. K-loop untouched (pipelining closed:
// r1/r2/r3/r8 all regressed — occupancy beats source pipelining at this size).
__global__ __launch_bounds__(256, 4) void pair_kernel(
        const char* __restrict__ EH, const char* __restrict__ EL,
        const char* __restrict__ SH, const char* __restrict__ SL,
        const char* __restrict__ Gp, const float* __restrict__ w1g,
        float* __restrict__ simval, float* __restrict__ out) {

    // lds: GEMM staging [EH 8K|EL 8K|SH 8K|SL 8K]=32K; then region0 = SsT(64x68 f32)/G(16K),
    // P (Phi 8K + Plo 8K) at 17408..33792
    __shared__ __align__(16) char lds[33792];
    __shared__ __align__(16) float mz[64];
    __shared__ float w12all[256], w2part[512];   // w2part[wn][pr*64+q]

    const int tid = threadIdx.x;
    // XCD-aware mapping
    const int bn = blockIdx.x;
    const int xcd = bn & 7, slot = bn >> 3;
    const int T = xcd * 8 + (slot >> 4);
    const int wp = slot & 15;
    const int bi = (T >> 3) * 4 + (wp >> 2);
    const int bj = (T & 7) * 4 + (wp & 3);
    const int i0 = bi * 2, j0 = bj * 2;

    const int wv = tid >> 6, lane = tid & 63;
    const int wq = wv >> 1, wn = wv & 1;
    const int quad = lane >> 4, ln = lane & 15;

    int aoff[4], boff[4];
    #pragma unroll
    for (int mi = 0; mi < 4; mi++) {
        int R = 64 * (mi >> 1) + 32 * wq + 16 * (mi & 1) + ln;
        aoff[mi] = R * 64 + ((quad + (R >> 1)) & 3) * 16;
    }
    #pragma unroll
    for (int ni = 0; ni < 4; ni++) {
        int R = 64 * (ni >> 1) + 32 * wn + 16 * (ni & 1) + ln;
        boff[ni] = 16384 + R * 64 + ((quad + (R >> 1)) & 3) * 16;
    }

    const char* gA; const char* gB; int ldoff;
    if (wv == 0)      { gA = EH + (size_t)j0 * 65536;       gB = EH + (size_t)(j0 + 1) * 65536; ldoff = 0; }
    else if (wv == 1) { gA = EL + (size_t)j0 * 65536;       gB = EL + (size_t)(j0 + 1) * 65536; ldoff = 8192; }
    else if (wv == 2) { gA = SH + (size_t)i0 * 65536;       gB = SH + (size_t)(i0 + 1) * 65536; ldoff = 16384; }
    else              { gA = SL + (size_t)i0 * 65536;       gB = SL + (size_t)(i0 + 1) * 65536; ldoff = 24576; }
    gA += lane * 16; gB += lane * 16;

    f32x4 acc[4][4];
    #pragma unroll
    for (int a = 0; a < 4; a++)
        #pragma unroll
        for (int b = 0; b < 4; b++) acc[a][b] = (f32x4){0.f, 0.f, 0.f, 0.f};

    for (int kc = 0; kc < 16; kc++) {
        #pragma unroll
        for (int n = 0; n < 4; n++) GLDS(gA + n * 1024, lds + ldoff + n * 1024);
        #pragma unroll
        for (int n = 0; n < 4; n++) GLDS(gB + n * 1024, lds + ldoff + 4096 + n * 1024);
        gA += 4096; gB += 4096;
        __syncthreads();
        short8 bh[4], bl[4];
        #pragma unroll
        for (int ni = 0; ni < 4; ni++) {
            bh[ni] = *(const short8*)(lds + boff[ni]);
            bl[ni] = *(const short8*)(lds + boff[ni] + 8192);
        }
        #pragma unroll
        for (int mi = 0; mi < 4; mi++) {
            short8 ah = *(const short8*)(lds + aoff[mi]);
            short8 al = *(const short8*)(lds + aoff[mi] + 8192);
            #pragma unroll
            for (int ni = 0; ni < 4; ni++) {
                acc[mi][ni] = __builtin_amdgcn_mfma_f32_16x16x32_bf16(ah, bh[ni], acc[mi][ni], 0, 0, 0);
                acc[mi][ni] = __builtin_amdgcn_mfma_f32_16x16x32_bf16(ah, bl[ni], acc[mi][ni], 0, 0, 0);
                acc[mi][ni] = __builtin_amdgcn_mfma_f32_16x16x32_bf16(al, bh[ni], acc[mi][ni], 0, 0, 0);
            }
        }
        __syncthreads();
    }

    float* SsT = (float*)lds;          // [q][s], stride SST
    char*  Pb  = lds + 17408;          // Phi 8K + Plo 8K

    #pragma unroll
    for (int pr = 0; pr < 4; pr++) {
        const int a = pr >> 1, b = pr & 1;
        const int i = i0 + b, j = j0 + a;

        // C-write: SsT[q][s0..s0+3] b128 (f32x4 holds 4 consecutive rows s at col q)
        #pragma unroll
        for (int dm = 0; dm < 2; dm++)
            #pragma unroll
            for (int dn = 0; dn < 2; dn++) {
                int s0 = 32 * wq + 16 * dm + quad * 4;
                int q  = 32 * wn + 16 * dn + ln;
                *(f32x4*)(SsT + q * SST + s0) = acc[2 * a + dm][2 * b + dn];
            }
        __syncthreads();

        // softmax1 stats over q for each row s: mz[s] = m + ln(Z)
        // (t-order rotated per c: 4-way -> 2-way bank aliasing; max/sum order-free)
        {
            const int s = tid >> 2, c = tid & 3;
            float vv[16]; float m = -1e30f;
            #pragma unroll
            for (int t = 0; t < 16; t++) {
                int tt = (t + 4 * c) & 15;
                vv[t] = SsT[(16 * c + tt) * SST + s];
                m = fmaxf(m, vv[t]);
            }
            m = fmaxf(m, __shfl_xor(m, 1));
            m = fmaxf(m, __shfl_xor(m, 2));
            float sum = 0.f;
            #pragma unroll
            for (int t = 0; t < 16; t++) sum += __expf(vv[t] - m);
            sum += __shfl_xor(sum, 1);
            sum += __shfl_xor(sum, 2);
            if (c == 0) mz[s] = m + __logf(sum);
        }
        __syncthreads();

        // softmax2 over s (rows of SsT): P[q][s]; w12 fold in-reg; att_maps; pack P hi/lo
        {
            const int q = tid >> 2, c = tid & 3;
            float sc[16], at[16];
            #pragma unroll
            for (int r4 = 0; r4 < 4; r4++)
                *(f32x4*)(sc + 4 * r4) = *(const f32x4*)(SsT + q * SST + 16 * c + 4 * r4);
            float mzv[16];
            #pragma unroll
            for (int r4 = 0; r4 < 4; r4++)
                *(f32x4*)(mzv + 4 * r4) = *(const f32x4*)(mz + 16 * c + 4 * r4);
            float m2 = -1e30f;
            #pragma unroll
            for (int t = 0; t < 16; t++) {
                at[t] = __expf(sc[t] - mzv[t]);     // attn1
                m2 = fmaxf(m2, T1 * at[t]);
            }
            m2 = fmaxf(m2, __shfl_xor(m2, 1));
            m2 = fmaxf(m2, __shfl_xor(m2, 2));
            float sum = 0.f;
            #pragma unroll
            for (int t = 0; t < 16; t++) { at[t] = __expf(T1 * at[t] - m2); sum += at[t]; }
            sum += __shfl_xor(sum, 1);
            sum += __shfl_xor(sum, 2);
            float inv = 1.f / sum;
            float p12 = 0.f;
            #pragma unroll
            for (int t = 0; t < 16; t++) { at[t] *= inv; p12 += at[t] * sc[t]; }
            p12 += __shfl_xor(p12, 1);
            p12 += __shfl_xor(p12, 2);
            if (c == 0) w12all[pr * 64 + q] = p12;

            if (i == j) {
                float* om = out + 1 + (size_t)i * 4096;
                #pragma unroll
                for (int t = 0; t < 16; t++) om[q * 64 + c * 16 + t] = at[t];
            }

            uint hw[8], lw[8];
            #pragma unroll
            for (int e = 0; e < 8; e++) {
                ushort h0 = f2bf(at[2 * e]), h1 = f2bf(at[2 * e + 1]);
                hw[e] = (uint)h0 | ((uint)h1 << 16);
                ushort l0 = f2bf(at[2 * e] - bf2f(h0)), l1 = f2bf(at[2 * e + 1] - bf2f(h1));
                lw[e] = (uint)l0 | ((uint)l1 << 16);
            }
            int p0 = (2 * c + q) & 7, p1 = (2 * c + 1 + q) & 7;
            uint4 W;
            W.x = hw[0]; W.y = hw[1]; W.z = hw[2]; W.w = hw[3];
            *(uint4*)(Pb + q * 128 + p0 * 16) = W;
            W.x = hw[4]; W.y = hw[5]; W.z = hw[6]; W.w = hw[7];
            *(uint4*)(Pb + q * 128 + p1 * 16) = W;
            W.x = lw[0]; W.y = lw[1]; W.z = lw[2]; W.w = lw[3];
            *(uint4*)(Pb + 8192 + q * 128 + p0 * 16) = W;
            W.x = lw[4]; W.y = lw[5]; W.z = lw[6]; W.w = lw[7];
            *(uint4*)(Pb + 8192 + q * 128 + p1 * 16) = W;
        }
        __syncthreads();   // S dead; P visible

        // stage G_j into region0 via async GLDS (conflict-free, zero register cost)
        {
            const char* gs = Gp + (size_t)j * 16384 + wv * 4096 + lane * 16;
            char* gd = lds + wv * 4096;
            GLDS(gs,        gd);
            GLDS(gs + 1024, gd + 1024);
            GLDS(gs + 2048, gd + 2048);
            GLDS(gs + 3072, gd + 3072);
        }
        __syncthreads();   // G visible

        // quadratic: y = P * G (3-term)
        f32x4 acc2[2][2];
        #pragma unroll
        for (int x = 0; x < 2; x++)
            #pragma unroll
            for (int y = 0; y < 2; y++) acc2[x][y] = (f32x4){0.f, 0.f, 0.f, 0.f};
        #pragma unroll
        for (int ch = 0; ch < 2; ch++) {
            short8 pah[2], pal[2], gbh[2], gbl[2];
            #pragma unroll
            for (int m2i = 0; m2i < 2; m2i++) {
                int q = 32 * wq + 16 * m2i + ln;
                int ph = ((ch * 4 + quad) + q) & 7;
                pah[m2i] = *(const short8*)(Pb + q * 128 + ph * 16);
                pal[m2i] = *(const short8*)(Pb + 8192 + q * 128 + ph * 16);
            }
            #pragma unroll
            for (int n2i = 0; n2i < 2; n2i++) {
                int u = 32 * wn + 16 * n2i + ln;
                int ph = ((ch * 4 + quad) + u) & 7;
                gbh[n2i] = *(const short8*)(lds + u * 128 + ph * 16);
                gbl[n2i] = *(const short8*)(lds + 8192 + u * 128 + ph * 16);
            }
            #pragma unroll
            for (int m2i = 0; m2i < 2; m2i++)
                #pragma unroll
                for (int n2i = 0; n2i < 2; n2i++) {
                    acc2[m2i][n2i] = __builtin_amdgcn_mfma_f32_16x16x32_bf16(pah[m2i], gbh[n2i], acc2[m2i][n2i], 0, 0, 0);
                    acc2[m2i][n2i] = __builtin_amdgcn_mfma_f32_16x16x32_bf16(pah[m2i], gbl[n2i], acc2[m2i][n2i], 0, 0, 0);
                    acc2[m2i][n2i] = __builtin_amdgcn_mfma_f32_16x16x32_bf16(pal[m2i], gbh[n2i], acc2[m2i][n2i], 0, 0, 0);
                }
        }

        // in-reg fold (replaces yT round-trip + 2 barriers): lane holds
        // y[t][q] = acc2[m2i][n2i][rr] with t = 32wn+16n2i+ln, q = 32wq+16m2i+4quad+rr.
        // Read P[q][t] hi+lo as scalar u16; reduce over t: n2i in-reg, ln via shfl_xor
        // (16-lane groups), wn via w2part partials combined in the sim tail.
        {
            #pragma unroll
            for (int m2i = 0; m2i < 2; m2i++)
                #pragma unroll
                for (int rr = 0; rr < 4; rr++) {
                    int q = 32 * wq + 16 * m2i + 4 * quad + rr;
                    float s = 0.f;
                    #pragma unroll
                    for (int n2i = 0; n2i < 2; n2i++) {
                        int t = 32 * wn + 16 * n2i + ln;
                        int off = q * 128 + ((((t >> 3) + q) & 7) << 4) + ((t & 7) << 1);
                        float pv = bf2f(*(const ushort*)(Pb + off))
                                 + bf2f(*(const ushort*)(Pb + 8192 + off));
                        s += pv * acc2[m2i][n2i][rr];
                    }
                    s += __shfl_xor(s, 1);
                    s += __shfl_xor(s, 2);
                    s += __shfl_xor(s, 4);
                    s += __shfl_xor(s, 8);
                    if (ln == 0) w2part[wn * 256 + pr * 64 + q] = s;
                }
        }
        __syncthreads();   // region0(G)/Pb reads done; w2part visible; next pr may overwrite
    }

    // sim tail: wave wv handles pair wv in parallel
    {
        const int pr = wv;
        const int ii = i0 + (pr & 1), jj = j0 + (pr >> 1);
        float w2s = w2part[pr * 64 + lane] + w2part[256 + pr * 64 + lane];
        float w2 = sqrtf(fmaxf(w2s, 0.f));
        float cosv = w12all[pr * 64 + lane] / fmaxf(w1g[ii * 64 + lane] * w2, EPSF);
        float e = __expf(T2 * cosv);
        #pragma unroll
        for (int off = 32; off; off >>= 1) e += __shfl_down(e, off);
        if (lane == 0) simval[ii * 64 + jj] = T3 * __logf(e);
    }
}

// ---------------- loss from the 64x64 sim matrix (row/col LSE on separate waves) ----------------
__global__ __launch_bounds__(256) void loss_kernel(const float* __restrict__ val,
                                                   float* __restrict__ out) {
    __shared__ float v[4096];
    __shared__ float rlse[64], clse[64];
    const int tid = threadIdx.x;
    #pragma unroll
    for (int k = 0; k < 4; k++)
        ((float4*)v)[tid + k * 256] = ((const float4*)val)[tid + k * 256];
    __syncthreads();
    if (tid < 64) {                     // wave 0: row LSE
        int i = tid;
        float rmax = -1e30f;
        for (int jj = 0; jj < 64; jj++) rmax = fmaxf(rmax, v[i * 64 + jj]);
        float rs = 0.f;
        for (int jj = 0; jj < 64; jj++) rs += __expf(v[i * 64 + jj] - rmax);
        rlse[i] = rmax + __logf(rs);
    } else if (tid < 128) {             // wave 1: col LSE
        int i = tid - 64;
        float cmax = -1e30f;
        for (int jj = 0; jj < 64; jj++) cmax = fmaxf(cmax, v[jj * 64 + i]);
        float cs = 0.f;
        for (int jj = 0; jj < 64; jj++) cs += __expf(v[jj * 64 + i] - cmax);
        clse[i] = cmax + __logf(cs);
    }
    __syncthreads();
    if (tid < 64) {
        float part = 2.f * v[tid * 64 + tid] - rlse[tid] - clse[tid];
        #pragma unroll
        for (int off = 32; off; off >>= 1) part += __shfl_down(part, off);
        if (tid == 0) out[0] = -part / 128.f;
    }
}

extern "C" void kernel_launch(void* const* d_in, const int* in_sizes, int n_in,
                              void* d_out, int out_size, void* d_ws, size_t ws_size,
                              hipStream_t stream) {
    (void)in_sizes; (void)n_in; (void)out_size; (void)ws_size;
    const float* ecg  = (const float*)d_in[0];
    const float* sent = (const float*)d_in[1];
    float* out = (float*)d_out;

    char* ws = (char*)d_ws;
    float* w1v  = (float*)ws;                     // 16 KB
    float* simv = (float*)(ws + 16384);           // 16 KB
    char* EH = ws + 32768;                        // 4 MB each
    char* EL = EH + (size_t)64 * 65536;
    char* SH = EL + (size_t)64 * 65536;
    char* SL = SH + (size_t)64 * 65536;
    char* Gp = SL + (size_t)64 * 65536;           // 1 MB

    prep_kernel <<<128, 256, 0, stream>>>(ecg, sent, EH, EL, SH, SL, w1v);
    gprep_kernel<<<256, 256, 0, stream>>>(EH, EL, Gp);
    pair_kernel <<<1024, 256, 0, stream>>>(EH, EL, SH, SL, Gp, w1v, simv, out);
    loss_kernel <<<1,   256, 0, stream>>>(simv, out);
}

// Round 12
// 149.883 us; speedup vs baseline: 1.0406x; 1.0406x over previous
//
#include <hip/hip_runtime.h>
#include <math.h>

typedef __attribute__((ext_vector_type(8))) short short8;
typedef __attribute__((ext_vector_type(4))) float f32x4;
typedef unsigned int uint;
typedef unsigned short ushort;

#define T1 4.0f
#define T2 5.0f
#define T3 10.0f
#define EPSF 1e-8f
#define SST 68   // S^T / yT row stride (floats): rows 16B-aligned

__device__ inline ushort f2bf(float x) {
    union { float f; uint u; } a; a.f = x;
    uint r = a.u + 0x7FFFu + ((a.u >> 16) & 1u);
    return (ushort)(r >> 16);
}
__device__ inline float bf2f(ushort h) {
    union { uint u; float f; } a; a.u = ((uint)h) << 16;
    return a.f;
}

// async global->LDS, 16B per lane; LDS dest is wave-uniform base + lane*16 (implicit)
#define GLDS(gsrc, ldst) \
    __builtin_amdgcn_global_load_lds( \
        (const __attribute__((address_space(1))) uint*)(gsrc), \
        (__attribute__((address_space(3))) uint*)(ldst), 16, 0, 0)

// ---------------- prep: fp32 -> bf16 hi/lo in LDS-image layout (+ w1 norms) ----------------
// Layout per row-block idx: [kc 0..15][row r 0..63][4 chunks of 16B, logical chunk c at
// physical slot (c + (r>>1)) & 3]  => 65536 B per idx.  (kept separate from G-compute:
// r6->r7 showed fusing G into prep slowed pair 76.6->71 via L2-state effects)
__global__ __launch_bounds__(256) void prep_kernel(
        const float* __restrict__ ecg, const float* __restrict__ sent,
        char* __restrict__ EH, char* __restrict__ EL,
        char* __restrict__ SH, char* __restrict__ SL, float* __restrict__ w1) {
    __shared__ float partial[256];
    const int bid = blockIdx.x;
    const int tensor = bid >> 6, idx = bid & 63;
    const float* src = (tensor ? sent : ecg) + (size_t)idx * 32768;
    char* dh = (tensor ? SH : EH) + (size_t)idx * 65536;
    char* dl = (tensor ? SL : EL) + (size_t)idx * 65536;
    const int tid = threadIdx.x;
    const int r = tid & 63;
    float s2 = 0.f;
    #pragma unroll
    for (int it = 0; it < 4; it++) {
        int kc = it * 4 + (tid >> 6);
        const float* p = src + r * 512 + kc * 32;
        char* oh = dh + kc * 4096 + r * 64;
        char* ol = dl + kc * 4096 + r * 64;
        #pragma unroll
        for (int c = 0; c < 4; c++) {
            float4 v0 = *(const float4*)(p + c * 8);
            float4 v1 = *(const float4*)(p + c * 8 + 4);
            float x[8] = {v0.x, v0.y, v0.z, v0.w, v1.x, v1.y, v1.z, v1.w};
            uint hw[4], lw[4];
            #pragma unroll
            for (int e = 0; e < 4; e++) {
                float a0 = x[2 * e], a1 = x[2 * e + 1];
                ushort h0 = f2bf(a0), h1 = f2bf(a1);
                hw[e] = (uint)h0 | ((uint)h1 << 16);
                ushort l0 = f2bf(a0 - bf2f(h0)), l1 = f2bf(a1 - bf2f(h1));
                lw[e] = (uint)l0 | ((uint)l1 << 16);
                s2 += a0 * a0 + a1 * a1;
            }
            int phys = (c + (r >> 1)) & 3;
            uint4 H; H.x = hw[0]; H.y = hw[1]; H.z = hw[2]; H.w = hw[3];
            *(uint4*)(oh + phys * 16) = H;
            uint4 L; L.x = lw[0]; L.y = lw[1]; L.z = lw[2]; L.w = lw[3];
            *(uint4*)(ol + phys * 16) = L;
        }
    }
    partial[tid] = s2;
    __syncthreads();
    if (tensor == 1 && tid < 64) {
        float t = partial[tid] + partial[tid + 64] + partial[tid + 128] + partial[tid + 192];
        w1[idx * 64 + tid] = sqrtf(t);
    }
}

// ---------------- G_j = E_j E_j^T, barrier-free, 256 blocks (r8, kept: -3.4us non-pair) ----------------
// block b: j = b>>2, row band tq = b&3 (16 rows). Wave w: output cols 16w..16w+16.
// Fragments read directly from global (L2-hot). No LDS, no barriers -> latency-pipelined.
__global__ __launch_bounds__(256) void gprep_kernel(
        const char* __restrict__ EH, const char* __restrict__ EL, char* __restrict__ Gp) {
    const int b = blockIdx.x;
    const int j = b >> 2, tq = b & 3;
    const int tid = threadIdx.x;
    const int wv = tid >> 6, lane = tid & 63;
    const int quad = lane >> 4, ln = lane & 15;
    const char* srcH = EH + (size_t)j * 65536;
    const char* srcL = EL + (size_t)j * 65536;

    const int Ra = 16 * tq + ln;
    const int ao = Ra * 64 + ((quad + (Ra >> 1)) & 3) * 16;
    const int Rb = 16 * wv + ln;
    const int bo = Rb * 64 + ((quad + (Rb >> 1)) & 3) * 16;

    f32x4 acc = (f32x4){0.f, 0.f, 0.f, 0.f};
    #pragma unroll 4
    for (int kc = 0; kc < 16; kc++) {
        const char* ph = srcH + (size_t)kc * 4096;
        const char* pl = srcL + (size_t)kc * 4096;
        short8 ah = *(const short8*)(ph + ao);
        short8 al = *(const short8*)(pl + ao);
        short8 bh = *(const short8*)(ph + bo);
        short8 bl = *(const short8*)(pl + bo);
        acc = __builtin_amdgcn_mfma_f32_16x16x32_bf16(ah, bh, acc, 0, 0, 0);
        acc = __builtin_amdgcn_mfma_f32_16x16x32_bf16(ah, bl, acc, 0, 0, 0);
        acc = __builtin_amdgcn_mfma_f32_16x16x32_bf16(al, bh, acc, 0, 0, 0);
    }
    #pragma unroll
    for (int rr = 0; rr < 4; rr++) {
        int t = 16 * tq + quad * 4 + rr;
        int u = 16 * wv + ln;
        float g = acc[rr];
        ushort h = f2bf(g);
        ushort l = f2bf(g - bf2f(h));
        char* base = Gp + (size_t)j * 16384 + t * 128 + (((u >> 3) + t) & 7) * 16 + (u & 7) * 2;
        *(ushort*)base = h;
        *(ushort*)(base + 8192) = l;
    }
}

// ---------------- main: one block per 2x2 pairs (128x128 GEMM1 tile) ----------------
// r9 final (measured 70.5-70.7us pair, 147.3us total — session best): r0 structure
// (16x16x32, 16-kc loop, f32x4 acc[4][4], 4 blocks/CU) + GLDS G-stage + softmax1
// t-rotation. Closed experiment ledger: K-loop pipelining (r1/r2/r3/r8: all 76-77us,
// occupancy beats source pipelining at this size); prep fusion (r1-r6: +6us to pair);
// epilogue restructuring (r1/r2/r4/r11 etc: 6 failures, all spill-mediated — the
// r0-shape epilogue exactly saturates the 128-reg budget; any added live state spills).
__global__ __launch_bounds__(256, 4) void pair_kernel(
        const char* __restrict__ EH, const char* __restrict__ EL,
        const char* __restrict__ SH, const char* __restrict__ SL,
        const char* __restrict__ Gp, const float* __restrict__ w1g,
        float* __restrict__ simval, float* __restrict__ out) {

    // lds: GEMM staging [EH 8K|EL 8K|SH 8K|SL 8K]=32K; then region0 = SsT(64x68 f32)/G(16K)/yT,
    // P (Phi 8K + Plo 8K) at 17408..33792
    __shared__ __align__(16) char lds[33792];
    __shared__ __align__(16) float mz[64];
    __shared__ float w12all[256], w2all[256];

    const int tid = threadIdx.x;
    // XCD-aware mapping
    const int bn = blockIdx.x;
    const int xcd = bn & 7, slot = bn >> 3;
    const int T = xcd * 8 + (slot >> 4);
    const int wp = slot & 15;
    const int bi = (T >> 3) * 4 + (wp >> 2);
    const int bj = (T & 7) * 4 + (wp & 3);
    const int i0 = bi * 2, j0 = bj * 2;

    const int wv = tid >> 6, lane = tid & 63;
    const int wq = wv >> 1, wn = wv & 1;
    const int quad = lane >> 4, ln = lane & 15;

    int aoff[4], boff[4];
    #pragma unroll
    for (int mi = 0; mi < 4; mi++) {
        int R = 64 * (mi >> 1) + 32 * wq + 16 * (mi & 1) + ln;
        aoff[mi] = R * 64 + ((quad + (R >> 1)) & 3) * 16;
    }
    #pragma unroll
    for (int ni = 0; ni < 4; ni++) {
        int R = 64 * (ni >> 1) + 32 * wn + 16 * (ni & 1) + ln;
        boff[ni] = 16384 + R * 64 + ((quad + (R >> 1)) & 3) * 16;
    }

    const char* gA; const char* gB; int ldoff;
    if (wv == 0)      { gA = EH + (size_t)j0 * 65536;       gB = EH + (size_t)(j0 + 1) * 65536; ldoff = 0; }
    else if (wv == 1) { gA = EL + (size_t)j0 * 65536;       gB = EL + (size_t)(j0 + 1) * 65536; ldoff = 8192; }
    else if (wv == 2) { gA = SH + (size_t)i0 * 65536;       gB = SH + (size_t)(i0 + 1) * 65536; ldoff = 16384; }
    else              { gA = SL + (size_t)i0 * 65536;       gB = SL + (size_t)(i0 + 1) * 65536; ldoff = 24576; }
    gA += lane * 16; gB += lane * 16;

    f32x4 acc[4][4];
    #pragma unroll
    for (int a = 0; a < 4; a++)
        #pragma unroll
        for (int b = 0; b < 4; b++) acc[a][b] = (f32x4){0.f, 0.f, 0.f, 0.f};

    for (int kc = 0; kc < 16; kc++) {
        #pragma unroll
        for (int n = 0; n < 4; n++) GLDS(gA + n * 1024, lds + ldoff + n * 1024);
        #pragma unroll
        for (int n = 0; n < 4; n++) GLDS(gB + n * 1024, lds + ldoff + 4096 + n * 1024);
        gA += 4096; gB += 4096;
        __syncthreads();
        short8 bh[4], bl[4];
        #pragma unroll
        for (int ni = 0; ni < 4; ni++) {
            bh[ni] = *(const short8*)(lds + boff[ni]);
            bl[ni] = *(const short8*)(lds + boff[ni] + 8192);
        }
        #pragma unroll
        for (int mi = 0; mi < 4; mi++) {
            short8 ah = *(const short8*)(lds + aoff[mi]);
            short8 al = *(const short8*)(lds + aoff[mi] + 8192);
            #pragma unroll
            for (int ni = 0; ni < 4; ni++) {
                acc[mi][ni] = __builtin_amdgcn_mfma_f32_16x16x32_bf16(ah, bh[ni], acc[mi][ni], 0, 0, 0);
                acc[mi][ni] = __builtin_amdgcn_mfma_f32_16x16x32_bf16(ah, bl[ni], acc[mi][ni], 0, 0, 0);
                acc[mi][ni] = __builtin_amdgcn_mfma_f32_16x16x32_bf16(al, bh[ni], acc[mi][ni], 0, 0, 0);
            }
        }
        __syncthreads();
    }

    float* SsT = (float*)lds;          // [q][s], stride SST
    float* yT  = (float*)lds;          // [t][q], stride SST (aliases)
    char*  Pb  = lds + 17408;          // Phi 8K + Plo 8K

    #pragma unroll
    for (int pr = 0; pr < 4; pr++) {
        const int a = pr >> 1, b = pr & 1;
        const int i = i0 + b, j = j0 + a;

        // C-write: SsT[q][s0..s0+3] b128 (f32x4 holds 4 consecutive rows s at col q)
        #pragma unroll
        for (int dm = 0; dm < 2; dm++)
            #pragma unroll
            for (int dn = 0; dn < 2; dn++) {
                int s0 = 32 * wq + 16 * dm + quad * 4;
                int q  = 32 * wn + 16 * dn + ln;
                *(f32x4*)(SsT + q * SST + s0) = acc[2 * a + dm][2 * b + dn];
            }
        __syncthreads();

        // softmax1 stats over q for each row s: mz[s] = m + ln(Z)
        // (t-order rotated per c: 4-way -> 2-way bank aliasing; max/sum order-free)
        {
            const int s = tid >> 2, c = tid & 3;
            float vv[16]; float m = -1e30f;
            #pragma unroll
            for (int t = 0; t < 16; t++) {
                int tt = (t + 4 * c) & 15;
                vv[t] = SsT[(16 * c + tt) * SST + s];
                m = fmaxf(m, vv[t]);
            }
            m = fmaxf(m, __shfl_xor(m, 1));
            m = fmaxf(m, __shfl_xor(m, 2));
            float sum = 0.f;
            #pragma unroll
            for (int t = 0; t < 16; t++) sum += __expf(vv[t] - m);
            sum += __shfl_xor(sum, 1);
            sum += __shfl_xor(sum, 2);
            if (c == 0) mz[s] = m + __logf(sum);
        }
        __syncthreads();

        // softmax2 over s (rows of SsT): P[q][s]; w12 fold in-reg; att_maps; pack P hi/lo
        {
            const int q = tid >> 2, c = tid & 3;
            float sc[16], at[16];
            #pragma unroll
            for (int r4 = 0; r4 < 4; r4++)
                *(f32x4*)(sc + 4 * r4) = *(const f32x4*)(SsT + q * SST + 16 * c + 4 * r4);
            float mzv[16];
            #pragma unroll
            for (int r4 = 0; r4 < 4; r4++)
                *(f32x4*)(mzv + 4 * r4) = *(const f32x4*)(mz + 16 * c + 4 * r4);
            float m2 = -1e30f;
            #pragma unroll
            for (int t = 0; t < 16; t++) {
                at[t] = __expf(sc[t] - mzv[t]);     // attn1
                m2 = fmaxf(m2, T1 * at[t]);
            }
            m2 = fmaxf(m2, __shfl_xor(m2, 1));
            m2 = fmaxf(m2, __shfl_xor(m2, 2));
            float sum = 0.f;
            #pragma unroll
            for (int t = 0; t < 16; t++) { at[t] = __expf(T1 * at[t] - m2); sum += at[t]; }
            sum += __shfl_xor(sum, 1);
            sum += __shfl_xor(sum, 2);
            float inv = 1.f / sum;
            float p12 = 0.f;
            #pragma unroll
            for (int t = 0; t < 16; t++) { at[t] *= inv; p12 += at[t] * sc[t]; }
            p12 += __shfl_xor(p12, 1);
            p12 += __shfl_xor(p12, 2);
            if (c == 0) w12all[pr * 64 + q] = p12;

            if (i == j) {
                float* om = out + 1 + (size_t)i * 4096;
                #pragma unroll
                for (int t = 0; t < 16; t++) om[q * 64 + c * 16 + t] = at[t];
            }

            uint hw[8], lw[8];
            #pragma unroll
            for (int e = 0; e < 8; e++) {
                ushort h0 = f2bf(at[2 * e]), h1 = f2bf(at[2 * e + 1]);
                hw[e] = (uint)h0 | ((uint)h1 << 16);
                ushort l0 = f2bf(at[2 * e] - bf2f(h0)), l1 = f2bf(at[2 * e + 1] - bf2f(h1));
                lw[e] = (uint)l0 | ((uint)l1 << 16);
            }
            int p0 = (2 * c + q) & 7, p1 = (2 * c + 1 + q) & 7;
            uint4 W;
            W.x = hw[0]; W.y = hw[1]; W.z = hw[2]; W.w = hw[3];
            *(uint4*)(Pb + q * 128 + p0 * 16) = W;
            W.x = hw[4]; W.y = hw[5]; W.z = hw[6]; W.w = hw[7];
            *(uint4*)(Pb + q * 128 + p1 * 16) = W;
            W.x = lw[0]; W.y = lw[1]; W.z = lw[2]; W.w = lw[3];
            *(uint4*)(Pb + 8192 + q * 128 + p0 * 16) = W;
            W.x = lw[4]; W.y = lw[5]; W.z = lw[6]; W.w = lw[7];
            *(uint4*)(Pb + 8192 + q * 128 + p1 * 16) = W;
        }
        __syncthreads();   // S dead; P visible

        // stage G_j into region0 via async GLDS (conflict-free, zero register cost)
        {
            const char* gs = Gp + (size_t)j * 16384 + wv * 4096 + lane * 16;
            char* gd = lds + wv * 4096;
            GLDS(gs,        gd);
            GLDS(gs + 1024, gd + 1024);
            GLDS(gs + 2048, gd + 2048);
            GLDS(gs + 3072, gd + 3072);
        }
        __syncthreads();   // G visible

        // quadratic: y = P * G (3-term)
        f32x4 acc2[2][2];
        #pragma unroll
        for (int x = 0; x < 2; x++)
            #pragma unroll
            for (int y = 0; y < 2; y++) acc2[x][y] = (f32x4){0.f, 0.f, 0.f, 0.f};
        #pragma unroll
        for (int ch = 0; ch < 2; ch++) {
            short8 pah[2], pal[2], gbh[2], gbl[2];
            #pragma unroll
            for (int m2i = 0; m2i < 2; m2i++) {
                int q = 32 * wq + 16 * m2i + ln;
                int ph = ((ch * 4 + quad) + q) & 7;
                pah[m2i] = *(const short8*)(Pb + q * 128 + ph * 16);
                pal[m2i] = *(const short8*)(Pb + 8192 + q * 128 + ph * 16);
            }
            #pragma unroll
            for (int n2i = 0; n2i < 2; n2i++) {
                int u = 32 * wn + 16 * n2i + ln;
                int ph = ((ch * 4 + quad) + u) & 7;
                gbh[n2i] = *(const short8*)(lds + u * 128 + ph * 16);
                gbl[n2i] = *(const short8*)(lds + 8192 + u * 128 + ph * 16);
            }
            #pragma unroll
            for (int m2i = 0; m2i < 2; m2i++)
                #pragma unroll
                for (int n2i = 0; n2i < 2; n2i++) {
                    acc2[m2i][n2i] = __builtin_amdgcn_mfma_f32_16x16x32_bf16(pah[m2i], gbh[n2i], acc2[m2i][n2i], 0, 0, 0);
                    acc2[m2i][n2i] = __builtin_amdgcn_mfma_f32_16x16x32_bf16(pah[m2i], gbl[n2i], acc2[m2i][n2i], 0, 0, 0);
                    acc2[m2i][n2i] = __builtin_amdgcn_mfma_f32_16x16x32_bf16(pal[m2i], gbh[n2i], acc2[m2i][n2i], 0, 0, 0);
                }
        }
        __syncthreads();   // G reads done

        // yT[t][q0..q0+3] b128 (f32x4 holds 4 consecutive q at col t)
        #pragma unroll
        for (int m2i = 0; m2i < 2; m2i++)
            #pragma unroll
            for (int n2i = 0; n2i < 2; n2i++) {
                int q0 = 32 * wq + 16 * m2i + quad * 4;
                int t  = 32 * wn + 16 * n2i + ln;
                *(f32x4*)(yT + t * SST + q0) = acc2[m2i][n2i];
            }
        __syncthreads();

        // fold: w2all[q] = sum_t y[q][t] * P[q][t]  (round-0 exact: small live set)
        {
            const int q = tid >> 2, c = tid & 3;
            int p0 = (2 * c + q) & 7, p1 = (2 * c + 1 + q) & 7;
            uint4 H0 = *(const uint4*)(Pb + q * 128 + p0 * 16);
            uint4 H1 = *(const uint4*)(Pb + q * 128 + p1 * 16);
            uint4 L0 = *(const uint4*)(Pb + 8192 + q * 128 + p0 * 16);
            uint4 L1 = *(const uint4*)(Pb + 8192 + q * 128 + p1 * 16);
            uint hw[8] = {H0.x,H0.y,H0.z,H0.w, H1.x,H1.y,H1.z,H1.w};
            uint lw[8] = {L0.x,L0.y,L0.z,L0.w, L1.x,L1.y,L1.z,L1.w};
            float s = 0.f;
            #pragma unroll
            for (int e = 0; e < 8; e++) {
                float q0v = bf2f((ushort)(hw[e] & 0xFFFFu)) + bf2f((ushort)(lw[e] & 0xFFFFu));
                float q1v = bf2f((ushort)(hw[e] >> 16))     + bf2f((ushort)(lw[e] >> 16));
                s += q0v * yT[(16 * c + 2 * e) * SST + q];
                s += q1v * yT[(16 * c + 2 * e + 1) * SST + q];
            }
            s += __shfl_xor(s, 1);
            s += __shfl_xor(s, 2);
            if (c == 0) w2all[pr * 64 + q] = s;
        }
        __syncthreads();   // yT reads done; next pair may overwrite region 0 and Pb
    }

    // sim tail: wave wv handles pair wv in parallel
    {
        const int pr = wv;
        const int ii = i0 + (pr & 1), jj = j0 + (pr >> 1);
        float w2 = sqrtf(fmaxf(w2all[pr * 64 + lane], 0.f));
        float cosv = w12all[pr * 64 + lane] / fmaxf(w1g[ii * 64 + lane] * w2, EPSF);
        float e = __expf(T2 * cosv);
        #pragma unroll
        for (int off = 32; off; off >>= 1) e += __shfl_down(e, off);
        if (lane == 0) simval[ii * 64 + jj] = T3 * __logf(e);
    }
}

// ---------------- loss from the 64x64 sim matrix (row/col LSE on separate waves) ----------------
__global__ __launch_bounds__(256) void loss_kernel(const float* __restrict__ val,
                                                   float* __restrict__ out) {
    __shared__ float v[4096];
    __shared__ float rlse[64], clse[64];
    const int tid = threadIdx.x;
    #pragma unroll
    for (int k = 0; k < 4; k++)
        ((float4*)v)[tid + k * 256] = ((const float4*)val)[tid + k * 256];
    __syncthreads();
    if (tid < 64) {                     // wave 0: row LSE
        int i = tid;
        float rmax = -1e30f;
        for (int jj = 0; jj < 64; jj++) rmax = fmaxf(rmax, v[i * 64 + jj]);
        float rs = 0.f;
        for (int jj = 0; jj < 64; jj++) rs += __expf(v[i * 64 + jj] - rmax);
        rlse[i] = rmax + __logf(rs);
    } else if (tid < 128) {             // wave 1: col LSE
        int i = tid - 64;
        float cmax = -1e30f;
        for (int jj = 0; jj < 64; jj++) cmax = fmaxf(cmax, v[jj * 64 + i]);
        float cs = 0.f;
        for (int jj = 0; jj < 64; jj++) cs += __expf(v[jj * 64 + i] - cmax);
        clse[i] = cmax + __logf(cs);
    }
    __syncthreads();
    if (tid < 64) {
        float part = 2.f * v[tid * 64 + tid] - rlse[tid] - clse[tid];
        #pragma unroll
        for (int off = 32; off; off >>= 1) part += __shfl_down(part, off);
        if (tid == 0) out[0] = -part / 128.f;
    }
}

extern "C" void kernel_launch(void* const* d_in, const int* in_sizes, int n_in,
                              void* d_out, int out_size, void* d_ws, size_t ws_size,
                              hipStream_t stream) {
    (void)in_sizes; (void)n_in; (void)out_size; (void)ws_size;
    const float* ecg  = (const float*)d_in[0];
    const float* sent = (const float*)d_in[1];
    float* out = (float*)d_out;

    char* ws = (char*)d_ws;
    float* w1v  = (float*)ws;                     // 16 KB
    float* simv = (float*)(ws + 16384);           // 16 KB
    char* EH = ws + 32768;                        // 4 MB each
    char* EL = EH + (size_t)64 * 65536;
    char* SH = EL + (size_t)64 * 65536;
    char* SL = SH + (size_t)64 * 65536;
    char* Gp = SL + (size_t)64 * 65536;           // 1 MB

    prep_kernel <<<128, 256, 0, stream>>>(ecg, sent, EH, EL, SH, SL, w1v);
    gprep_kernel<<<256, 256, 0, stream>>>(EH, EL, Gp);
    pair_kernel <<<1024, 256, 0, stream>>>(EH, EL, SH, SL, Gp, w1v, simv, out);
    loss_kernel <<<1,   256, 0, stream>>>(simv, out);
}

// Round 13
// 143.983 us; speedup vs baseline: 1.0833x; 1.0410x over previous
//
#include <hip/hip_runtime.h>
#include <math.h>

typedef __attribute__((ext_vector_type(8))) short short8;
typedef __attribute__((ext_vector_type(4))) float f32x4;
typedef unsigned int uint;
typedef unsigned short ushort;

#define T1 4.0f
#define T2 5.0f
#define T3 10.0f
#define EPSF 1e-8f
#define SST 68   // S^T / yT row stride (floats): rows 16B-aligned

__device__ inline ushort f2bf(float x) {
    union { float f; uint u; } a; a.f = x;
    uint r = a.u + 0x7FFFu + ((a.u >> 16) & 1u);
    return (ushort)(r >> 16);
}
__device__ inline float bf2f(ushort h) {
    union { uint u; float f; } a; a.u = ((uint)h) << 16;
    return a.f;
}

// async global->LDS, 16B per lane; LDS dest is wave-uniform base + lane*16 (implicit)
#define GLDS(gsrc, ldst) \
    __builtin_amdgcn_global_load_lds( \
        (const __attribute__((address_space(1))) uint*)(gsrc), \
        (__attribute__((address_space(3))) uint*)(ldst), 16, 0, 0)

// ---------------- prep: fp32 -> bf16 hi/lo in LDS-image layout (+ w1 norms) ----------------
// Layout per row-block idx: [kc 0..15][row r 0..63][4 chunks of 16B, logical chunk c at
// physical slot (c + (r>>1)) & 3]  => 65536 B per idx.
// r13: 512 blocks (tensor x idx x row-quarter), 8 waves/CU — prep was at 2 waves/CU
// (latency-hiding starved for a memory-bound kernel, G1/G11). Thread = (row, kc):
// 16 lanes/row, each converts one 32-col kc-chunk; w1 via 16-lane shfl reduce.
// No LDS, no barriers. (Kept separate from G-compute: r6->r7 fusion slowed pair +6us.)
__global__ __launch_bounds__(256) void prep_kernel(
        const float* __restrict__ ecg, const float* __restrict__ sent,
        char* __restrict__ EH, char* __restrict__ EL,
        char* __restrict__ SH, char* __restrict__ SL, float* __restrict__ w1) {
    const int b = blockIdx.x;
    const int tensor = b >> 8, idx = (b >> 2) & 63, qt = b & 3;
    const float* src = (tensor ? sent : ecg) + (size_t)idx * 32768;
    char* dh = (tensor ? SH : EH) + (size_t)idx * 65536;
    char* dl = (tensor ? SL : EL) + (size_t)idx * 65536;
    const int tid = threadIdx.x;
    const int r = qt * 16 + (tid >> 4);   // rows lane-contiguous: 16 lanes per row
    const int kc = tid & 15;
    const float* p = src + r * 512 + kc * 32;
    char* oh = dh + kc * 4096 + r * 64;
    char* ol = dl + kc * 4096 + r * 64;
    float s2 = 0.f;
    #pragma unroll
    for (int c = 0; c < 4; c++) {
        float4 v0 = *(const float4*)(p + c * 8);
        float4 v1 = *(const float4*)(p + c * 8 + 4);
        float x[8] = {v0.x, v0.y, v0.z, v0.w, v1.x, v1.y, v1.z, v1.w};
        uint hw[4], lw[4];
        #pragma unroll
        for (int e = 0; e < 4; e++) {
            float a0 = x[2 * e], a1 = x[2 * e + 1];
            ushort h0 = f2bf(a0), h1 = f2bf(a1);
            hw[e] = (uint)h0 | ((uint)h1 << 16);
            ushort l0 = f2bf(a0 - bf2f(h0)), l1 = f2bf(a1 - bf2f(h1));
            lw[e] = (uint)l0 | ((uint)l1 << 16);
            s2 += a0 * a0 + a1 * a1;
        }
        int phys = (c + (r >> 1)) & 3;
        uint4 H; H.x = hw[0]; H.y = hw[1]; H.z = hw[2]; H.w = hw[3];
        *(uint4*)(oh + phys * 16) = H;
        uint4 L; L.x = lw[0]; L.y = lw[1]; L.z = lw[2]; L.w = lw[3];
        *(uint4*)(ol + phys * 16) = L;
    }
    // row-norm: reduce s2 over the 16 kc-lanes of this row (lane-contiguous groups)
    s2 += __shfl_xor(s2, 1);
    s2 += __shfl_xor(s2, 2);
    s2 += __shfl_xor(s2, 4);
    s2 += __shfl_xor(s2, 8);
    if (tensor == 1 && kc == 0) w1[idx * 64 + r] = sqrtf(s2);
}

// ---------------- G_j = E_j E_j^T, barrier-free, 256 blocks (r8, kept: -3.4us non-pair) ----------------
// block b: j = b>>2, row band tq = b&3 (16 rows). Wave w: output cols 16w..16w+16.
// Fragments read directly from global (L2-hot). No LDS, no barriers -> latency-pipelined.
__global__ __launch_bounds__(256) void gprep_kernel(
        const char* __restrict__ EH, const char* __restrict__ EL, char* __restrict__ Gp) {
    const int b = blockIdx.x;
    const int j = b >> 2, tq = b & 3;
    const int tid = threadIdx.x;
    const int wv = tid >> 6, lane = tid & 63;
    const int quad = lane >> 4, ln = lane & 15;
    const char* srcH = EH + (size_t)j * 65536;
    const char* srcL = EL + (size_t)j * 65536;

    const int Ra = 16 * tq + ln;
    const int ao = Ra * 64 + ((quad + (Ra >> 1)) & 3) * 16;
    const int Rb = 16 * wv + ln;
    const int bo = Rb * 64 + ((quad + (Rb >> 1)) & 3) * 16;

    f32x4 acc = (f32x4){0.f, 0.f, 0.f, 0.f};
    #pragma unroll 4
    for (int kc = 0; kc < 16; kc++) {
        const char* ph = srcH + (size_t)kc * 4096;
        const char* pl = srcL + (size_t)kc * 4096;
        short8 ah = *(const short8*)(ph + ao);
        short8 al = *(const short8*)(pl + ao);
        short8 bh = *(const short8*)(ph + bo);
        short8 bl = *(const short8*)(pl + bo);
        acc = __builtin_amdgcn_mfma_f32_16x16x32_bf16(ah, bh, acc, 0, 0, 0);
        acc = __builtin_amdgcn_mfma_f32_16x16x32_bf16(ah, bl, acc, 0, 0, 0);
        acc = __builtin_amdgcn_mfma_f32_16x16x32_bf16(al, bh, acc, 0, 0, 0);
    }
    #pragma unroll
    for (int rr = 0; rr < 4; rr++) {
        int t = 16 * tq + quad * 4 + rr;
        int u = 16 * wv + ln;
        float g = acc[rr];
        ushort h = f2bf(g);
        ushort l = f2bf(g - bf2f(h));
        char* base = Gp + (size_t)j * 16384 + t * 128 + (((u >> 3) + t) & 7) * 16 + (u & 7) * 2;
        *(ushort*)base = h;
        *(ushort*)(base + 8192) = l;
    }
}

// ---------------- main: one block per 2x2 pairs (128x128 GEMM1 tile) ----------------
// r9/r12 verified best (pair 70.5-71.8us): r0 structure (16x16x32, 16-kc loop, f32x4
// acc[4][4], 4 blocks/CU) + GLDS G-stage + softmax1 t-rotation. Closed ledger:
// K-loop pipelining (r1/r2/r3/r8: regressed — occupancy beats source pipelining here);
// prep fusion (+6us to pair); epilogue restructuring (6 spill-mediated failures — the
// r0-shape epilogue exactly saturates the 128-reg budget).
__global__ __launch_bounds__(256, 4) void pair_kernel(
        const char* __restrict__ EH, const char* __restrict__ EL,
        const char* __restrict__ SH, const char* __restrict__ SL,
        const char* __restrict__ Gp, const float* __restrict__ w1g,
        float* __restrict__ simval, float* __restrict__ out) {

    // lds: GEMM staging [EH 8K|EL 8K|SH 8K|SL 8K]=32K; then region0 = SsT(64x68 f32)/G(16K)/yT,
    // P (Phi 8K + Plo 8K) at 17408..33792
    __shared__ __align__(16) char lds[33792];
    __shared__ __align__(16) float mz[64];
    __shared__ float w12all[256], w2all[256];

    const int tid = threadIdx.x;
    // XCD-aware mapping
    const int bn = blockIdx.x;
    const int xcd = bn & 7, slot = bn >> 3;
    const int T = xcd * 8 + (slot >> 4);
    const int wp = slot & 15;
    const int bi = (T >> 3) * 4 + (wp >> 2);
    const int bj = (T & 7) * 4 + (wp & 3);
    const int i0 = bi * 2, j0 = bj * 2;

    const int wv = tid >> 6, lane = tid & 63;
    const int wq = wv >> 1, wn = wv & 1;
    const int quad = lane >> 4, ln = lane & 15;

    int aoff[4], boff[4];
    #pragma unroll
    for (int mi = 0; mi < 4; mi++) {
        int R = 64 * (mi >> 1) + 32 * wq + 16 * (mi & 1) + ln;
        aoff[mi] = R * 64 + ((quad + (R >> 1)) & 3) * 16;
    }
    #pragma unroll
    for (int ni = 0; ni < 4; ni++) {
        int R = 64 * (ni >> 1) + 32 * wn + 16 * (ni & 1) + ln;
        boff[ni] = 16384 + R * 64 + ((quad + (R >> 1)) & 3) * 16;
    }

    const char* gA; const char* gB; int ldoff;
    if (wv == 0)      { gA = EH + (size_t)j0 * 65536;       gB = EH + (size_t)(j0 + 1) * 65536; ldoff = 0; }
    else if (wv == 1) { gA = EL + (size_t)j0 * 65536;       gB = EL + (size_t)(j0 + 1) * 65536; ldoff = 8192; }
    else if (wv == 2) { gA = SH + (size_t)i0 * 65536;       gB = SH + (size_t)(i0 + 1) * 65536; ldoff = 16384; }
    else              { gA = SL + (size_t)i0 * 65536;       gB = SL + (size_t)(i0 + 1) * 65536; ldoff = 24576; }
    gA += lane * 16; gB += lane * 16;

    f32x4 acc[4][4];
    #pragma unroll
    for (int a = 0; a < 4; a++)
        #pragma unroll
        for (int b = 0; b < 4; b++) acc[a][b] = (f32x4){0.f, 0.f, 0.f, 0.f};

    for (int kc = 0; kc < 16; kc++) {
        #pragma unroll
        for (int n = 0; n < 4; n++) GLDS(gA + n * 1024, lds + ldoff + n * 1024);
        #pragma unroll
        for (int n = 0; n < 4; n++) GLDS(gB + n * 1024, lds + ldoff + 4096 + n * 1024);
        gA += 4096; gB += 4096;
        __syncthreads();
        short8 bh[4], bl[4];
        #pragma unroll
        for (int ni = 0; ni < 4; ni++) {
            bh[ni] = *(const short8*)(lds + boff[ni]);
            bl[ni] = *(const short8*)(lds + boff[ni] + 8192);
        }
        #pragma unroll
        for (int mi = 0; mi < 4; mi++) {
            short8 ah = *(const short8*)(lds + aoff[mi]);
            short8 al = *(const short8*)(lds + aoff[mi] + 8192);
            #pragma unroll
            for (int ni = 0; ni < 4; ni++) {
                acc[mi][ni] = __builtin_amdgcn_mfma_f32_16x16x32_bf16(ah, bh[ni], acc[mi][ni], 0, 0, 0);
                acc[mi][ni] = __builtin_amdgcn_mfma_f32_16x16x32_bf16(ah, bl[ni], acc[mi][ni], 0, 0, 0);
                acc[mi][ni] = __builtin_amdgcn_mfma_f32_16x16x32_bf16(al, bh[ni], acc[mi][ni], 0, 0, 0);
            }
        }
        __syncthreads();
    }

    float* SsT = (float*)lds;          // [q][s], stride SST
    float* yT  = (float*)lds;          // [t][q], stride SST (aliases)
    char*  Pb  = lds + 17408;          // Phi 8K + Plo 8K

    #pragma unroll
    for (int pr = 0; pr < 4; pr++) {
        const int a = pr >> 1, b = pr & 1;
        const int i = i0 + b, j = j0 + a;

        // C-write: SsT[q][s0..s0+3] b128 (f32x4 holds 4 consecutive rows s at col q)
        #pragma unroll
        for (int dm = 0; dm < 2; dm++)
            #pragma unroll
            for (int dn = 0; dn < 2; dn++) {
                int s0 = 32 * wq + 16 * dm + quad * 4;
                int q  = 32 * wn + 16 * dn + ln;
                *(f32x4*)(SsT + q * SST + s0) = acc[2 * a + dm][2 * b + dn];
            }
        __syncthreads();

        // softmax1 stats over q for each row s: mz[s] = m + ln(Z)
        // (t-order rotated per c: 4-way -> 2-way bank aliasing; max/sum order-free)
        {
            const int s = tid >> 2, c = tid & 3;
            float vv[16]; float m = -1e30f;
            #pragma unroll
            for (int t = 0; t < 16; t++) {
                int tt = (t + 4 * c) & 15;
                vv[t] = SsT[(16 * c + tt) * SST + s];
                m = fmaxf(m, vv[t]);
            }
            m = fmaxf(m, __shfl_xor(m, 1));
            m = fmaxf(m, __shfl_xor(m, 2));
            float sum = 0.f;
            #pragma unroll
            for (int t = 0; t < 16; t++) sum += __expf(vv[t] - m);
            sum += __shfl_xor(sum, 1);
            sum += __shfl_xor(sum, 2);
            if (c == 0) mz[s] = m + __logf(sum);
        }
        __syncthreads();

        // softmax2 over s (rows of SsT): P[q][s]; w12 fold in-reg; att_maps; pack P hi/lo
        {
            const int q = tid >> 2, c = tid & 3;
            float sc[16], at[16];
            #pragma unroll
            for (int r4 = 0; r4 < 4; r4++)
                *(f32x4*)(sc + 4 * r4) = *(const f32x4*)(SsT + q * SST + 16 * c + 4 * r4);
            float mzv[16];
            #pragma unroll
            for (int r4 = 0; r4 < 4; r4++)
                *(f32x4*)(mzv + 4 * r4) = *(const f32x4*)(mz + 16 * c + 4 * r4);
            float m2 = -1e30f;
            #pragma unroll
            for (int t = 0; t < 16; t++) {
                at[t] = __expf(sc[t] - mzv[t]);     // attn1
                m2 = fmaxf(m2, T1 * at[t]);
            }
            m2 = fmaxf(m2, __shfl_xor(m2, 1));
            m2 = fmaxf(m2, __shfl_xor(m2, 2));
            float sum = 0.f;
            #pragma unroll
            for (int t = 0; t < 16; t++) { at[t] = __expf(T1 * at[t] - m2); sum += at[t]; }
            sum += __shfl_xor(sum, 1);
            sum += __shfl_xor(sum, 2);
            float inv = 1.f / sum;
            float p12 = 0.f;
            #pragma unroll
            for (int t = 0; t < 16; t++) { at[t] *= inv; p12 += at[t] * sc[t]; }
            p12 += __shfl_xor(p12, 1);
            p12 += __shfl_xor(p12, 2);
            if (c == 0) w12all[pr * 64 + q] = p12;

            if (i == j) {
                float* om = out + 1 + (size_t)i * 4096;
                #pragma unroll
                for (int t = 0; t < 16; t++) om[q * 64 + c * 16 + t] = at[t];
            }

            uint hw[8], lw[8];
            #pragma unroll
            for (int e = 0; e < 8; e++) {
                ushort h0 = f2bf(at[2 * e]), h1 = f2bf(at[2 * e + 1]);
                hw[e] = (uint)h0 | ((uint)h1 << 16);
                ushort l0 = f2bf(at[2 * e] - bf2f(h0)), l1 = f2bf(at[2 * e + 1] - bf2f(h1));
                lw[e] = (uint)l0 | ((uint)l1 << 16);
            }
            int p0 = (2 * c + q) & 7, p1 = (2 * c + 1 + q) & 7;
            uint4 W;
            W.x = hw[0]; W.y = hw[1]; W.z = hw[2]; W.w = hw[3];
            *(uint4*)(Pb + q * 128 + p0 * 16) = W;
            W.x = hw[4]; W.y = hw[5]; W.z = hw[6]; W.w = hw[7];
            *(uint4*)(Pb + q * 128 + p1 * 16) = W;
            W.x = lw[0]; W.y = lw[1]; W.z = lw[2]; W.w = lw[3];
            *(uint4*)(Pb + 8192 + q * 128 + p0 * 16) = W;
            W.x = lw[4]; W.y = lw[5]; W.z = lw[6]; W.w = lw[7];
            *(uint4*)(Pb + 8192 + q * 128 + p1 * 16) = W;
        }
        __syncthreads();   // S dead; P visible

        // stage G_j into region0 via async GLDS (conflict-free, zero register cost)
        {
            const char* gs = Gp + (size_t)j * 16384 + wv * 4096 + lane * 16;
            char* gd = lds + wv * 4096;
            GLDS(gs,        gd);
            GLDS(gs + 1024, gd + 1024);
            GLDS(gs + 2048, gd + 2048);
            GLDS(gs + 3072, gd + 3072);
        }
        __syncthreads();   // G visible

        // quadratic: y = P * G (3-term)
        f32x4 acc2[2][2];
        #pragma unroll
        for (int x = 0; x < 2; x++)
            #pragma unroll
            for (int y = 0; y < 2; y++) acc2[x][y] = (f32x4){0.f, 0.f, 0.f, 0.f};
        #pragma unroll
        for (int ch = 0; ch < 2; ch++) {
            short8 pah[2], pal[2], gbh[2], gbl[2];
            #pragma unroll
            for (int m2i = 0; m2i < 2; m2i++) {
                int q = 32 * wq + 16 * m2i + ln;
                int ph = ((ch * 4 + quad) + q) & 7;
                pah[m2i] = *(const short8*)(Pb + q * 128 + ph * 16);
                pal[m2i] = *(const short8*)(Pb + 8192 + q * 128 + ph * 16);
            }
            #pragma unroll
            for (int n2i = 0; n2i < 2; n2i++) {
                int u = 32 * wn + 16 * n2i + ln;
                int ph = ((ch * 4 + quad) + u) & 7;
                gbh[n2i] = *(const short8*)(lds + u * 128 + ph * 16);
                gbl[n2i] = *(const short8*)(lds + 8192 + u * 128 + ph * 16);
            }
            #pragma unroll
            for (int m2i = 0; m2i < 2; m2i++)
                #pragma unroll
                for (int n2i = 0; n2i < 2; n2i++) {
                    acc2[m2i][n2i] = __builtin_amdgcn_mfma_f32_16x16x32_bf16(pah[m2i], gbh[n2i], acc2[m2i][n2i], 0, 0, 0);
                    acc2[m2i][n2i] = __builtin_amdgcn_mfma_f32_16x16x32_bf16(pah[m2i], gbl[n2i], acc2[m2i][n2i], 0, 0, 0);
                    acc2[m2i][n2i] = __builtin_amdgcn_mfma_f32_16x16x32_bf16(pal[m2i], gbh[n2i], acc2[m2i][n2i], 0, 0, 0);
                }
        }
        __syncthreads();   // G reads done

        // yT[t][q0..q0+3] b128 (f32x4 holds 4 consecutive q at col t)
        #pragma unroll
        for (int m2i = 0; m2i < 2; m2i++)
            #pragma unroll
            for (int n2i = 0; n2i < 2; n2i++) {
                int q0 = 32 * wq + 16 * m2i + quad * 4;
                int t  = 32 * wn + 16 * n2i + ln;
                *(f32x4*)(yT + t * SST + q0) = acc2[m2i][n2i];
            }
        __syncthreads();

        // fold: w2all[q] = sum_t y[q][t] * P[q][t]  (round-0 exact: small live set)
        {
            const int q = tid >> 2, c = tid & 3;
            int p0 = (2 * c + q) & 7, p1 = (2 * c + 1 + q) & 7;
            uint4 H0 = *(const uint4*)(Pb + q * 128 + p0 * 16);
            uint4 H1 = *(const uint4*)(Pb + q * 128 + p1 * 16);
            uint4 L0 = *(const uint4*)(Pb + 8192 + q * 128 + p0 * 16);
            uint4 L1 = *(const uint4*)(Pb + 8192 + q * 128 + p1 * 16);
            uint hw[8] = {H0.x,H0.y,H0.z,H0.w, H1.x,H1.y,H1.z,H1.w};
            uint lw[8] = {L0.x,L0.y,L0.z,L0.w, L1.x,L1.y,L1.z,L1.w};
            float s = 0.f;
            #pragma unroll
            for (int e = 0; e < 8; e++) {
                float q0v = bf2f((ushort)(hw[e] & 0xFFFFu)) + bf2f((ushort)(lw[e] & 0xFFFFu));
                float q1v = bf2f((ushort)(hw[e] >> 16))     + bf2f((ushort)(lw[e] >> 16));
                s += q0v * yT[(16 * c + 2 * e) * SST + q];
                s += q1v * yT[(16 * c + 2 * e + 1) * SST + q];
            }
            s += __shfl_xor(s, 1);
            s += __shfl_xor(s, 2);
            if (c == 0) w2all[pr * 64 + q] = s;
        }
        __syncthreads();   // yT reads done; next pair may overwrite region 0 and Pb
    }

    // sim tail: wave wv handles pair wv in parallel
    {
        const int pr = wv;
        const int ii = i0 + (pr & 1), jj = j0 + (pr >> 1);
        float w2 = sqrtf(fmaxf(w2all[pr * 64 + lane], 0.f));
        float cosv = w12all[pr * 64 + lane] / fmaxf(w1g[ii * 64 + lane] * w2, EPSF);
        float e = __expf(T2 * cosv);
        #pragma unroll
        for (int off = 32; off; off >>= 1) e += __shfl_down(e, off);
        if (lane == 0) simval[ii * 64 + jj] = T3 * __logf(e);
    }
}

// ---------------- loss from the 64x64 sim matrix (row/col LSE on separate waves) ----------------
__global__ __launch_bounds__(256) void loss_kernel(const float* __restrict__ val,
                                                   float* __restrict__ out) {
    __shared__ float v[4096];
    __shared__ float rlse[64], clse[64];
    const int tid = threadIdx.x;
    #pragma unroll
    for (int k = 0; k < 4; k++)
        ((float4*)v)[tid + k * 256] = ((const float4*)val)[tid + k * 256];
    __syncthreads();
    if (tid < 64) {                     // wave 0: row LSE
        int i = tid;
        float rmax = -1e30f;
        for (int jj = 0; jj < 64; jj++) rmax = fmaxf(rmax, v[i * 64 + jj]);
        float rs = 0.f;
        for (int jj = 0; jj < 64; jj++) rs += __expf(v[i * 64 + jj] - rmax);
        rlse[i] = rmax + __logf(rs);
    } else if (tid < 128) {             // wave 1: col LSE
        int i = tid - 64;
        float cmax = -1e30f;
        for (int jj = 0; jj < 64; jj++) cmax = fmaxf(cmax, v[jj * 64 + i]);
        float cs = 0.f;
        for (int jj = 0; jj < 64; jj++) cs += __expf(v[jj * 64 + i] - cmax);
        clse[i] = cmax + __logf(cs);
    }
    __syncthreads();
    if (tid < 64) {
        float part = 2.f * v[tid * 64 + tid] - rlse[tid] - clse[tid];
        #pragma unroll
        for (int off = 32; off; off >>= 1) part += __shfl_down(part, off);
        if (tid == 0) out[0] = -part / 128.f;
    }
}

extern "C" void kernel_launch(void* const* d_in, const int* in_sizes, int n_in,
                              void* d_out, int out_size, void* d_ws, size_t ws_size,
                              hipStream_t stream) {
    (void)in_sizes; (void)n_in; (void)out_size; (void)ws_size;
    const float* ecg  = (const float*)d_in[0];
    const float* sent = (const float*)d_in[1];
    float* out = (float*)d_out;

    char* ws = (char*)d_ws;
    float* w1v  = (float*)ws;                     // 16 KB
    float* simv = (float*)(ws + 16384);           // 16 KB
    char* EH = ws + 32768;                        // 4 MB each
    char* EL = EH + (size_t)64 * 65536;
    char* SH = EL + (size_t)64 * 65536;
    char* SL = SH + (size_t)64 * 65536;
    char* Gp = SL + (size_t)64 * 65536;           // 1 MB

    prep_kernel <<<512, 256, 0, stream>>>(ecg, sent, EH, EL, SH, SL, w1v);
    gprep_kernel<<<256, 256, 0, stream>>>(EH, EL, Gp);
    pair_kernel <<<1024, 256, 0, stream>>>(EH, EL, SH, SL, Gp, w1v, simv, out);
    loss_kernel <<<1,   256, 0, stream>>>(simv, out);
}